// Round 4
// baseline (531.010 us; speedup 1.0000x reference)
//
#include <hip/hip_runtime.h>
#include <cstdint>

#define B_ 8
#define T_ 4096
#define TP1 4097
#define IN_ 512
#define H_ 512
#define N3H 1536
#define KD 1024
#define CHUNKS 256
#define CLEN 16   // T_/CHUNKS

typedef __attribute__((ext_vector_type(4))) float floatx4;
typedef __attribute__((ext_vector_type(4))) float f4;
typedef __attribute__((ext_vector_type(8))) short short8;
typedef __attribute__((ext_vector_type(4))) unsigned short us4;
typedef __attribute__((ext_vector_type(4))) _Float16 h4;

__device__ __forceinline__ unsigned short f2bf(float v){
  unsigned int u = __float_as_uint(v);
  unsigned int r = (u + 0x7fffu + ((u >> 16) & 1u)) >> 16;
  return (unsigned short)r;
}
__device__ __forceinline__ float sigm(float x){ return 1.f/(1.f + __expf(-x)); }
__device__ __forceinline__ float tanhf_(float x){ return 2.f*sigm(2.f*x) - 1.f; }

#define GLLS(src, dst) __builtin_amdgcn_global_load_lds( \
    (const __attribute__((address_space(1))) void*)(src), \
    (__attribute__((address_space(3))) void*)(dst), 16, 0, 0)

// x f32 [B,T,IN] -> xpad bf16 [B, T+1, IN] with zero row at t'=0 (causal pad)
__global__ void cast_pad_kernel(const float* __restrict__ x, unsigned short* __restrict__ xpad){
  int64_t i = (int64_t)blockIdx.x*256 + threadIdx.x;       // over B*TP1*(IN/4)
  const int64_t total = (int64_t)B_*TP1*(IN_/4);
  if (i >= total) return;
  int cg = (int)(i & 127);
  int64_t r = i >> 7;                                      // row (b*TP1 + t)
  int t = (int)(r % TP1);
  int b = (int)(r / TP1);
  us4 o;
  if (t == 0){ o = (us4){0,0,0,0}; }
  else {
    f4 v = *(const f4*)(x + ((int64_t)b*T_ + (t-1))*IN_ + cg*4);
    #pragma unroll
    for (int u=0;u<4;++u) o[u] = f2bf(v[u]);
  }
  *(us4*)(xpad + r*IN_ + cg*4) = o;
}

// w f32 [3H, IN, K=2] -> wt bf16 [3H, 1024], k-major halves; blockIdx.y picks layer
__global__ void wt_kernel(const float* __restrict__ wA, unsigned short* __restrict__ wtA,
                          const float* __restrict__ wB, unsigned short* __restrict__ wtB){
  int i = blockIdx.x*256 + threadIdx.x;                    // over N3H*512
  if (i >= N3H*512) return;
  const float* w = blockIdx.y ? wB : wA;
  unsigned short* wt = blockIdx.y ? wtB : wtA;
  int ci = i & 511;
  int o = i >> 9;
  const float* wp = w + (int64_t)o*KD + ci*2;
  wt[(int64_t)o*KD + ci]       = f2bf(wp[0]);
  wt[(int64_t)o*KD + 512 + ci] = f2bf(wp[1]);
}

// C[m][n] = sum_k A[m][k]*W[n][k], stored RAW f16 (bias+activation applied in scans).
// XCD-swizzled linear grid; BK=32 (m97 structure — known-good occupancy).
__global__ __launch_bounds__(256) void gemm_kernel(
    const unsigned short* __restrict__ A, const unsigned short* __restrict__ W,
    _Float16* __restrict__ C){
  __shared__ unsigned short As[128*32];
  __shared__ unsigned short Bs[128*32];
  const int tid = threadIdx.x;
  const int lane = tid & 63;
  const int wave = tid >> 6;
  const int bid = blockIdx.x;
  const int xcd = bid & 7;
  const int kb  = bid >> 3;              // 0..383
  const int colt = kb % 12;
  const int rowt = (kb / 12) * 8 + xcd;  // 0..255
  const int m0 = rowt * 128;
  const int n0 = colt * 128;
  const int bb = m0 / T_;                // tile fully inside one batch (128 | 4096)
  const unsigned short* aSrc = A + (int64_t)(m0 + bb + (tid>>2))*IN_ + (tid&3)*8;
  const unsigned short* bSrc = W + (int64_t)(n0 + (tid>>2))*KD + (tid&3)*8;
  unsigned short* aDst = As + tid*8;
  unsigned short* bDst = Bs + tid*8;
  const int wm = wave & 1;
  const int wn = wave >> 1;
  const int l16 = lane & 15;
  const int quad = lane >> 4;
  floatx4 acc[4][4];
  #pragma unroll
  for (int i=0;i<4;i++)
    #pragma unroll
    for (int j=0;j<4;j++) acc[i][j] = (floatx4){0.f,0.f,0.f,0.f};
  const unsigned short* aLds = As + (wm*64 + l16)*32 + quad*8;
  const unsigned short* bLds = Bs + (wn*64 + l16)*32 + quad*8;

  for (int kk = 0; kk < KD; kk += 32){
    __syncthreads();
    GLLS(aSrc + kk,           aDst);
    GLLS(aSrc + 64*IN_ + kk,  aDst + 2048);
    GLLS(bSrc + kk,           bDst);
    GLLS(bSrc + 64*KD + kk,   bDst + 2048);
    __syncthreads();
    short8 af[4], bfr[4];
    #pragma unroll
    for (int i=0;i<4;i++) af[i] = *(const short8*)(aLds + i*16*32);
    #pragma unroll
    for (int j=0;j<4;j++) bfr[j] = *(const short8*)(bLds + j*16*32);
    #pragma unroll
    for (int i=0;i<4;i++)
      #pragma unroll
      for (int j=0;j<4;j++)
        acc[i][j] = __builtin_amdgcn_mfma_f32_16x16x32_bf16(af[i], bfr[j], acc[i][j], 0, 0, 0);
  }
  #pragma unroll
  for (int i=0;i<4;i++){
    int row = m0 + wm*64 + i*16 + quad*4;
    #pragma unroll
    for (int j=0;j<4;j++){
      int col = n0 + wn*64 + j*16 + l16;
      _Float16* cp = C + (int64_t)row*N3H + col;
      #pragma unroll
      for (int r=0;r<4;r++) cp[(int64_t)r*N3H] = (_Float16)acc[i][j][r];
    }
  }
}

// phase 1: per-chunk affine composition (Aa, Bb): h_out = Aa*h_in + Bb
// conv holds RAW pre-activation values; bias+act applied here.
__global__ void scan_phase1(const _Float16* __restrict__ conv, const float* __restrict__ bias,
                            float* __restrict__ carA, float* __restrict__ carB){
  int q = blockIdx.x*256 + threadIdx.x;     // CHUNKS*8*128
  int chg = q & 127;
  int bq = (q >> 7) & 7;
  int c  = q >> 10;
  int ch = chg*4;
  f4 bz = *(const f4*)(bias + ch);
  f4 bf = *(const f4*)(bias + 512 + ch);
  f4 Aa = {1.f,1.f,1.f,1.f}, Bb = {0.f,0.f,0.f,0.f};
  const _Float16* p = conv + ((int64_t)bq*T_ + c*CLEN)*N3H + ch;
  for (int g=0; g<CLEN/8; ++g){
    h4 zb[8], fb[8];
    #pragma unroll
    for (int u=0;u<8;++u){
      zb[u] = *(const h4*)(p + (int64_t)u*N3H);
      fb[u] = *(const h4*)(p + (int64_t)u*N3H + 512);
    }
    #pragma unroll
    for (int u=0;u<8;++u){
      #pragma unroll
      for (int v=0;v<4;++v){
        float fv = sigm((float)fb[u][v] + bf[v]);
        float zv = tanhf_((float)zb[u][v] + bz[v]);
        Aa[v] *= fv;
        Bb[v] = fv*Bb[v] + (1.f-fv)*zv;
      }
    }
    p += (int64_t)8*N3H;
  }
  *(f4*)(carA + (int64_t)q*4) = Aa;
  *(f4*)(carB + (int64_t)q*4) = Bb;
}

// phase 2: scan over chunks; emit h at chunk starts + final hT
__global__ void scan_phase2(const float* __restrict__ carA, const float* __restrict__ carB,
                            float* __restrict__ hstart, float* __restrict__ hT){
  int q = blockIdx.x*256 + threadIdx.x;     // 1024 (4 channels each)
  f4 h = {0.f,0.f,0.f,0.f};
  for (int g=0; g<CHUNKS/8; ++g){
    f4 av[8], bv[8];
    #pragma unroll
    for (int u=0;u<8;++u){
      int64_t idx = (int64_t)(g*8+u)*4096 + q*4;
      av[u] = *(const f4*)(carA + idx);
      bv[u] = *(const f4*)(carB + idx);
    }
    #pragma unroll
    for (int u=0;u<8;++u){
      int64_t idx = (int64_t)(g*8+u)*4096 + q*4;
      *(f4*)(hstart + idx) = h;
      #pragma unroll
      for (int v=0;v<4;++v) h[v] = av[u][v]*h[v] + bv[u][v];
    }
  }
  *(f4*)(hT + (int64_t)q*4) = h;
}

// phase 3: replay chunk with true h-start, apply o*h, write output
template<int LAYER>
__global__ void scan_phase3(const _Float16* __restrict__ conv, const float* __restrict__ bias,
                            const float* __restrict__ hstart, unsigned short* __restrict__ xpad,
                            float* __restrict__ outf){
  int q = blockIdx.x*256 + threadIdx.x;     // CHUNKS*8*128
  int chg = q & 127;
  int bq = (q >> 7) & 7;
  int c  = q >> 10;
  int ch = chg*4;
  f4 bz = *(const f4*)(bias + ch);
  f4 bf = *(const f4*)(bias + 512 + ch);
  f4 bo = *(const f4*)(bias + 1024 + ch);
  f4 h = *(const f4*)(hstart + (int64_t)q*4);
  const _Float16* p = conv + ((int64_t)bq*T_ + c*CLEN)*N3H + ch;
  int t = c*CLEN;
  for (int g=0; g<CLEN/8; ++g){
    h4 zb[8], fb[8], ob[8];
    #pragma unroll
    for (int u=0;u<8;++u){
      zb[u] = *(const h4*)(p + (int64_t)u*N3H);
      fb[u] = *(const h4*)(p + (int64_t)u*N3H + 512);
      ob[u] = *(const h4*)(p + (int64_t)u*N3H + 1024);
    }
    #pragma unroll
    for (int u=0;u<8;++u){
      if (LAYER == 0){
        us4 ov4;
        #pragma unroll
        for (int v=0;v<4;++v){
          float fv = sigm((float)fb[u][v] + bf[v]);
          float zv = tanhf_((float)zb[u][v] + bz[v]);
          float ov = sigm((float)ob[u][v] + bo[v]);
          h[v] = fv*h[v] + (1.f-fv)*zv;
          ov4[v] = f2bf(ov*h[v]);
        }
        *(us4*)(xpad + ((int64_t)bq*TP1 + t+u + 1)*IN_ + ch) = ov4;
      } else {
        f4 of4;
        #pragma unroll
        for (int v=0;v<4;++v){
          float fv = sigm((float)fb[u][v] + bf[v]);
          float zv = tanhf_((float)zb[u][v] + bz[v]);
          float ov = sigm((float)ob[u][v] + bo[v]);
          h[v] = fv*h[v] + (1.f-fv)*zv;
          of4[v] = ov*h[v];
        }
        *(f4*)(outf + ((int64_t)bq*T_ + t+u)*H_ + ch) = of4;
      }
    }
    t += 8; p += (int64_t)8*N3H;
  }
}

extern "C" void kernel_launch(void* const* d_in, const int* in_sizes, int n_in,
                              void* d_out, int out_size, void* d_ws, size_t ws_size,
                              hipStream_t stream){
  const float* x  = (const float*)d_in[0];
  const float* w0 = (const float*)d_in[1];
  const float* b0 = (const float*)d_in[2];
  const float* w1 = (const float*)d_in[3];
  const float* b1 = (const float*)d_in[4];
  float* out = (float*)d_out;

  char* ws = (char*)d_ws;
  size_t off = 0;
  auto alloc = [&](size_t bytes)->char*{
    char* p = ws + off; off = (off + bytes + 255) & ~(size_t)255; return p; };
  unsigned short* xpad = (unsigned short*)alloc((size_t)B_*TP1*IN_*2);
  unsigned short* Wt0  = (unsigned short*)alloc((size_t)N3H*KD*2);
  unsigned short* Wt1  = (unsigned short*)alloc((size_t)N3H*KD*2);
  _Float16* conv = (_Float16*)alloc((size_t)B_*T_*N3H*2);
  float* carA = (float*)alloc((size_t)CHUNKS*4096*4);
  float* carB = (float*)alloc((size_t)CHUNKS*4096*4);
  float* hst  = (float*)alloc((size_t)CHUNKS*4096*4);
  if (off > ws_size) return;  // workspace too small -> fail loudly in validation

  float* out_main = out;
  float* h0 = out + (int64_t)B_*T_*H_;
  float* h1 = h0 + B_*H_;

  const int64_t padN = (int64_t)B_*TP1*(IN_/4);
  cast_pad_kernel<<<(int)((padN + 255)/256), 256, 0, stream>>>(x, xpad);
  dim3 wgrid((N3H*512 + 255)/256, 2);
  wt_kernel<<<wgrid, 256, 0, stream>>>(w0, Wt0, w1, Wt1);

  const int ggrid = (N3H/128) * ((B_*T_)/128);   // 3072
  const int sgrid = (CHUNKS*8*128) / 256;        // 1024
  gemm_kernel<<<ggrid, 256, 0, stream>>>(xpad, Wt0, conv);
  scan_phase1<<<sgrid, 256, 0, stream>>>(conv, b0, carA, carB);
  scan_phase2<<<4, 256, 0, stream>>>(carA, carB, hst, h0);
  scan_phase3<0><<<sgrid, 256, 0, stream>>>(conv, b0, hst, xpad, nullptr);

  gemm_kernel<<<ggrid, 256, 0, stream>>>(xpad, Wt1, conv);
  scan_phase1<<<sgrid, 256, 0, stream>>>(conv, b1, carA, carB);
  scan_phase2<<<4, 256, 0, stream>>>(carA, carB, hst, h1);
  scan_phase3<1><<<sgrid, 256, 0, stream>>>(conv, b1, hst, nullptr, out_main);
}

// Round 5
// 458.027 us; speedup vs baseline: 1.1593x; 1.1593x over previous
//
#include <hip/hip_runtime.h>
#include <cstdint>

#define B_ 8
#define T_ 4096
#define TP1 4097
#define IN_ 512
#define H_ 512
#define N3H 1536
#define KD 1024
#define CHUNKS 64
#define CLEN 64   // T_/CHUNKS

typedef __attribute__((ext_vector_type(4))) float floatx4;
typedef __attribute__((ext_vector_type(4))) float f4;
typedef __attribute__((ext_vector_type(8))) short short8;
typedef __attribute__((ext_vector_type(4))) unsigned short us4;
typedef __attribute__((ext_vector_type(4))) _Float16 h4;

__device__ __forceinline__ unsigned short f2bf(float v){
  unsigned int u = __float_as_uint(v);
  unsigned int r = (u + 0x7fffu + ((u >> 16) & 1u)) >> 16;
  return (unsigned short)r;
}
// fast sigmoid: one v_exp_f32 + one v_rcp_f32 (no IEEE div sequence)
__device__ __forceinline__ float sigm(float x){
  return __builtin_amdgcn_rcpf(1.f + __expf(-x));
}
__device__ __forceinline__ float tanhf_(float x){ return 2.f*sigm(2.f*x) - 1.f; }

#define GLLS(src, dst) __builtin_amdgcn_global_load_lds( \
    (const __attribute__((address_space(1))) void*)(src), \
    (__attribute__((address_space(3))) void*)(dst), 16, 0, 0)

// x f32 [B,T,IN] -> xpad bf16 [B, T+1, IN] with zero row at t'=0 (causal pad)
__global__ void cast_pad_kernel(const float* __restrict__ x, unsigned short* __restrict__ xpad){
  int64_t i = (int64_t)blockIdx.x*256 + threadIdx.x;       // over B*TP1*(IN/4)
  const int64_t total = (int64_t)B_*TP1*(IN_/4);
  if (i >= total) return;
  int cg = (int)(i & 127);
  int64_t r = i >> 7;                                      // row (b*TP1 + t)
  int t = (int)(r % TP1);
  int b = (int)(r / TP1);
  us4 o;
  if (t == 0){ o = (us4){0,0,0,0}; }
  else {
    f4 v = *(const f4*)(x + ((int64_t)b*T_ + (t-1))*IN_ + cg*4);
    #pragma unroll
    for (int u=0;u<4;++u) o[u] = f2bf(v[u]);
  }
  *(us4*)(xpad + r*IN_ + cg*4) = o;
}

// w f32 [3H, IN, K=2] -> wt bf16 [3H, 1024], k-major halves; blockIdx.y picks layer
__global__ void wt_kernel(const float* __restrict__ wA, unsigned short* __restrict__ wtA,
                          const float* __restrict__ wB, unsigned short* __restrict__ wtB){
  int i = blockIdx.x*256 + threadIdx.x;                    // over N3H*512
  if (i >= N3H*512) return;
  const float* w = blockIdx.y ? wB : wA;
  unsigned short* wt = blockIdx.y ? wtB : wtA;
  int ci = i & 511;
  int o = i >> 9;
  const float* wp = w + (int64_t)o*KD + ci*2;
  wt[(int64_t)o*KD + ci]       = f2bf(wp[0]);
  wt[(int64_t)o*KD + 512 + ci] = f2bf(wp[1]);
}

// C[m][n] = act(sum_k A[m][k]*W[n][k] + bias[n]) stored f16.
// XCD-swizzled linear grid; BK=32 (m97 structure); fast rcp-based activations.
__global__ __launch_bounds__(256) void gemm_kernel(
    const unsigned short* __restrict__ A, const unsigned short* __restrict__ W,
    const float* __restrict__ bias, _Float16* __restrict__ C){
  __shared__ unsigned short As[128*32];
  __shared__ unsigned short Bs[128*32];
  const int tid = threadIdx.x;
  const int lane = tid & 63;
  const int wave = tid >> 6;
  const int bid = blockIdx.x;
  const int xcd = bid & 7;
  const int kb  = bid >> 3;              // 0..383
  const int colt = kb % 12;
  const int rowt = (kb / 12) * 8 + xcd;  // 0..255
  const int m0 = rowt * 128;
  const int n0 = colt * 128;
  const int bb = m0 / T_;                // tile fully inside one batch (128 | 4096)
  const int act = n0 >> 9;               // 0=z(tanh), 1=f(sigm), 2=o(sigm)
  const unsigned short* aSrc = A + (int64_t)(m0 + bb + (tid>>2))*IN_ + (tid&3)*8;
  const unsigned short* bSrc = W + (int64_t)(n0 + (tid>>2))*KD + (tid&3)*8;
  unsigned short* aDst = As + tid*8;
  unsigned short* bDst = Bs + tid*8;
  const int wm = wave & 1;
  const int wn = wave >> 1;
  const int l16 = lane & 15;
  const int quad = lane >> 4;
  floatx4 acc[4][4];
  #pragma unroll
  for (int i=0;i<4;i++)
    #pragma unroll
    for (int j=0;j<4;j++) acc[i][j] = (floatx4){0.f,0.f,0.f,0.f};
  const unsigned short* aLds = As + (wm*64 + l16)*32 + quad*8;
  const unsigned short* bLds = Bs + (wn*64 + l16)*32 + quad*8;

  for (int kk = 0; kk < KD; kk += 32){
    __syncthreads();
    GLLS(aSrc + kk,           aDst);
    GLLS(aSrc + 64*IN_ + kk,  aDst + 2048);
    GLLS(bSrc + kk,           bDst);
    GLLS(bSrc + 64*KD + kk,   bDst + 2048);
    __syncthreads();
    short8 af[4], bfr[4];
    #pragma unroll
    for (int i=0;i<4;i++) af[i] = *(const short8*)(aLds + i*16*32);
    #pragma unroll
    for (int j=0;j<4;j++) bfr[j] = *(const short8*)(bLds + j*16*32);
    #pragma unroll
    for (int i=0;i<4;i++)
      #pragma unroll
      for (int j=0;j<4;j++)
        acc[i][j] = __builtin_amdgcn_mfma_f32_16x16x32_bf16(af[i], bfr[j], acc[i][j], 0, 0, 0);
  }
  float bv[4];
  #pragma unroll
  for (int j=0;j<4;j++) bv[j] = bias[n0 + wn*64 + j*16 + l16];
  #pragma unroll
  for (int i=0;i<4;i++){
    int row = m0 + wm*64 + i*16 + quad*4;
    #pragma unroll
    for (int j=0;j<4;j++){
      int col = n0 + wn*64 + j*16 + l16;
      _Float16* cp = C + (int64_t)row*N3H + col;
      #pragma unroll
      for (int r=0;r<4;r++){
        float v = acc[i][j][r] + bv[j];
        v = (act == 0) ? tanhf_(v) : sigm(v);
        cp[(int64_t)r*N3H] = (_Float16)v;
      }
    }
  }
}

// phase 1: per-chunk affine composition (Aa, Bb): h_out = Aa*h_in + Bb
__global__ void scan_phase1(const _Float16* __restrict__ conv,
                            float* __restrict__ carA, float* __restrict__ carB){
  int q = blockIdx.x*256 + threadIdx.x;     // CHUNKS*8*128 = 65536
  int chg = q & 127;
  int bq = (q >> 7) & 7;
  int c  = q >> 10;
  int ch = chg*4;
  f4 Aa = {1.f,1.f,1.f,1.f}, Bb = {0.f,0.f,0.f,0.f};
  const _Float16* p = conv + ((int64_t)bq*T_ + c*CLEN)*N3H + ch;
  for (int g=0; g<CLEN/8; ++g){
    h4 zb[8], fb[8];
    #pragma unroll
    for (int u=0;u<8;++u){
      zb[u] = *(const h4*)(p + (int64_t)u*N3H);
      fb[u] = *(const h4*)(p + (int64_t)u*N3H + 512);
    }
    #pragma unroll
    for (int u=0;u<8;++u){
      #pragma unroll
      for (int v=0;v<4;++v){
        float fv = (float)fb[u][v];
        float zv = (float)zb[u][v];
        Aa[v] *= fv;
        Bb[v] = fv*Bb[v] + (1.f-fv)*zv;
      }
    }
    p += (int64_t)8*N3H;
  }
  *(f4*)(carA + (int64_t)q*4) = Aa;
  *(f4*)(carB + (int64_t)q*4) = Bb;
}

// phase 2: scan over chunks; emit h at chunk starts + final hT. 1 channel/thread.
__global__ void scan_phase2(const float* __restrict__ carA, const float* __restrict__ carB,
                            float* __restrict__ hstart, float* __restrict__ hT){
  int q = blockIdx.x*256 + threadIdx.x;     // 4096 channels (b*512+ch)
  float h = 0.f;
  for (int c=0;c<CHUNKS;++c){
    int64_t idx = (int64_t)c*4096 + q;
    hstart[idx] = h;
    h = carA[idx]*h + carB[idx];
  }
  hT[q] = h;
}

// phase 3: replay chunk with true h-start, apply o*h, write output
template<int LAYER>
__global__ void scan_phase3(const _Float16* __restrict__ conv,
                            const float* __restrict__ hstart, unsigned short* __restrict__ xpad,
                            float* __restrict__ outf){
  int q = blockIdx.x*256 + threadIdx.x;     // 65536
  int chg = q & 127;
  int bq = (q >> 7) & 7;
  int c  = q >> 10;
  int ch = chg*4;
  f4 h;
  #pragma unroll
  for (int v=0;v<4;++v) h[v] = hstart[(int64_t)c*4096 + bq*512 + ch + v];
  const _Float16* p = conv + ((int64_t)bq*T_ + c*CLEN)*N3H + ch;
  int t = c*CLEN;
  for (int g=0; g<CLEN/8; ++g){
    h4 zb[8], fb[8], ob[8];
    #pragma unroll
    for (int u=0;u<8;++u){
      zb[u] = *(const h4*)(p + (int64_t)u*N3H);
      fb[u] = *(const h4*)(p + (int64_t)u*N3H + 512);
      ob[u] = *(const h4*)(p + (int64_t)u*N3H + 1024);
    }
    #pragma unroll
    for (int u=0;u<8;++u){
      if (LAYER == 0){
        us4 ov4;
        #pragma unroll
        for (int v=0;v<4;++v){
          float fv = (float)fb[u][v];
          h[v] = fv*h[v] + (1.f-fv)*(float)zb[u][v];
          ov4[v] = f2bf((float)ob[u][v]*h[v]);
        }
        *(us4*)(xpad + ((int64_t)bq*TP1 + t+u + 1)*IN_ + ch) = ov4;
      } else {
        f4 of4;
        #pragma unroll
        for (int v=0;v<4;++v){
          float fv = (float)fb[u][v];
          h[v] = fv*h[v] + (1.f-fv)*(float)zb[u][v];
          of4[v] = (float)ob[u][v]*h[v];
        }
        *(f4*)(outf + ((int64_t)bq*T_ + t+u)*H_ + ch) = of4;
      }
    }
    t += 8; p += (int64_t)8*N3H;
  }
}

extern "C" void kernel_launch(void* const* d_in, const int* in_sizes, int n_in,
                              void* d_out, int out_size, void* d_ws, size_t ws_size,
                              hipStream_t stream){
  const float* x  = (const float*)d_in[0];
  const float* w0 = (const float*)d_in[1];
  const float* b0 = (const float*)d_in[2];
  const float* w1 = (const float*)d_in[3];
  const float* b1 = (const float*)d_in[4];
  float* out = (float*)d_out;

  char* ws = (char*)d_ws;
  size_t off = 0;
  auto alloc = [&](size_t bytes)->char*{
    char* p = ws + off; off = (off + bytes + 255) & ~(size_t)255; return p; };
  unsigned short* xpad = (unsigned short*)alloc((size_t)B_*TP1*IN_*2);
  unsigned short* Wt0  = (unsigned short*)alloc((size_t)N3H*KD*2);
  unsigned short* Wt1  = (unsigned short*)alloc((size_t)N3H*KD*2);
  _Float16* conv = (_Float16*)alloc((size_t)B_*T_*N3H*2);
  float* carA = (float*)alloc((size_t)CHUNKS*4096*4);
  float* carB = (float*)alloc((size_t)CHUNKS*4096*4);
  float* hst  = (float*)alloc((size_t)CHUNKS*4096*4);
  if (off > ws_size) return;  // workspace too small -> fail loudly in validation

  float* out_main = out;
  float* h0 = out + (int64_t)B_*T_*H_;
  float* h1 = h0 + B_*H_;

  const int64_t padN = (int64_t)B_*TP1*(IN_/4);
  cast_pad_kernel<<<(int)((padN + 255)/256), 256, 0, stream>>>(x, xpad);
  dim3 wgrid((N3H*512 + 255)/256, 2);
  wt_kernel<<<wgrid, 256, 0, stream>>>(w0, Wt0, w1, Wt1);

  const int ggrid = (N3H/128) * ((B_*T_)/128);   // 3072
  const int sgrid = (CHUNKS*8*128) / 256;        // 256
  gemm_kernel<<<ggrid, 256, 0, stream>>>(xpad, Wt0, b0, conv);
  scan_phase1<<<sgrid, 256, 0, stream>>>(conv, carA, carB);
  scan_phase2<<<16, 256, 0, stream>>>(carA, carB, hst, h0);
  scan_phase3<0><<<sgrid, 256, 0, stream>>>(conv, hst, xpad, nullptr);

  gemm_kernel<<<ggrid, 256, 0, stream>>>(xpad, Wt1, b1, conv);
  scan_phase1<<<sgrid, 256, 0, stream>>>(conv, carA, carB);
  scan_phase2<<<16, 256, 0, stream>>>(carA, carB, hst, h1);
  scan_phase3<1><<<sgrid, 256, 0, stream>>>(conv, hst, nullptr, out_main);
}